// Round 1
// baseline (1605.758 us; speedup 1.0000x reference)
//
#include <hip/hip_runtime.h>
#include <math.h>

// Problem dims
#define LSEQ 256
#define NB   128
#define EMBD 300
#define PRJ  200

// ---------------------------------------------------------------------------
// Generic tiled f32 GEMM: C[bz] = act(A[bz] @ op(B[bz]) [+C_old] [+bias]) [*mask]
// 64x64 tile, BK=16, 256 threads, 4x4 accum per thread.
// A: row-major MxK (lda). B: row-major KxN (ldb) or, if TB, row-major NxK.
// ---------------------------------------------------------------------------
template<bool TB, bool BIAS, bool RELU, bool ACC, bool MASKE>
__global__ __launch_bounds__(256)
void gemm64(const float* __restrict__ A, int lda, long long sA,
            const float* __restrict__ B, int ldb, long long sB,
            float* __restrict__ C, int ldc, long long sC,
            const float* __restrict__ bias,
            const float* __restrict__ m1, const float* __restrict__ m2,
            int M, int N, int K)
{
    __shared__ float As[16][64];
    __shared__ float Bs[16][64];
    const int bz = blockIdx.z;
    const float* Ab = A + (long long)bz * sA;
    const float* Bb = B + (long long)bz * sB;
    float* Cb = C + (long long)bz * sC;
    const int m0 = blockIdx.y * 64;
    const int n0 = blockIdx.x * 64;
    const int t = threadIdx.x;
    const int tm = (t >> 4) << 2;   // 0..12, row group
    const int tn = (t & 15) << 2;   // 0..60, col group
    float acc[4][4] = {{0.f}};

    for (int k0 = 0; k0 < K; k0 += 16) {
        // ---- stage A tile: As[k][m] = A[m0+m][k0+k]
        {
            const int m  = t >> 2;
            const int kq = (t & 3) << 2;
            const int gm = m0 + m;
            const int gk = k0 + kq;
            if (gm < M && gk + 3 < K) {
                const float4 v = *reinterpret_cast<const float4*>(Ab + (long long)gm * lda + gk);
                As[kq+0][m] = v.x; As[kq+1][m] = v.y; As[kq+2][m] = v.z; As[kq+3][m] = v.w;
            } else {
#pragma unroll
                for (int i = 0; i < 4; ++i)
                    As[kq+i][m] = (gm < M && gk + i < K) ? Ab[(long long)gm * lda + gk + i] : 0.f;
            }
        }
        // ---- stage B tile: Bs[k][n]
        if (TB) {
            const int n  = t >> 2;
            const int kq = (t & 3) << 2;
            const int gn = n0 + n;
            const int gk = k0 + kq;
            if (gn < N && gk + 3 < K) {
                const float4 v = *reinterpret_cast<const float4*>(Bb + (long long)gn * ldb + gk);
                Bs[kq+0][n] = v.x; Bs[kq+1][n] = v.y; Bs[kq+2][n] = v.z; Bs[kq+3][n] = v.w;
            } else {
#pragma unroll
                for (int i = 0; i < 4; ++i)
                    Bs[kq+i][n] = (gn < N && gk + i < K) ? Bb[(long long)gn * ldb + gk + i] : 0.f;
            }
        } else {
            const int kk = t >> 4;
            const int nn = (t & 15) << 2;
            const int gk = k0 + kk;
            const int gn = n0 + nn;
            if (gk < K && gn + 3 < N) {
                *reinterpret_cast<float4*>(&Bs[kk][nn]) =
                    *reinterpret_cast<const float4*>(Bb + (long long)gk * ldb + gn);
            } else {
#pragma unroll
                for (int i = 0; i < 4; ++i)
                    Bs[kk][nn+i] = (gk < K && gn + i < N) ? Bb[(long long)gk * ldb + gn + i] : 0.f;
            }
        }
        __syncthreads();
#pragma unroll
        for (int kk = 0; kk < 16; ++kk) {
            const float4 av = *reinterpret_cast<const float4*>(&As[kk][tm]);
            const float4 bv = *reinterpret_cast<const float4*>(&Bs[kk][tn]);
            const float a[4] = {av.x, av.y, av.z, av.w};
            const float b[4] = {bv.x, bv.y, bv.z, bv.w};
#pragma unroll
            for (int i = 0; i < 4; ++i)
#pragma unroll
                for (int j = 0; j < 4; ++j)
                    acc[i][j] = fmaf(a[i], b[j], acc[i][j]);
        }
        __syncthreads();
    }

#pragma unroll
    for (int i = 0; i < 4; ++i) {
        const int gm = m0 + tm + i;
        if (gm >= M) continue;
#pragma unroll
        for (int j = 0; j < 4; ++j) {
            const int gn = n0 + tn + j;
            if (gn >= N) continue;
            float v = acc[i][j];
            if (ACC)  v += Cb[(long long)gm * ldc + gn];
            if (BIAS) v += bias[gn];
            if (RELU) v = fmaxf(v, 0.f);
            if (MASKE) v *= m1[(long long)bz * M + gm] * m2[(long long)bz * N + gn];
            Cb[(long long)gm * ldc + gn] = v;
        }
    }
}

// ---------------------------------------------------------------------------
// mask[b][l] = (l < count_nonzero(x[b,:])) ? 1 : 0   (tf.sequence_mask semantics)
// ---------------------------------------------------------------------------
__global__ __launch_bounds__(256)
void make_mask(const int* __restrict__ x, float* __restrict__ mask)
{
    const int b = blockIdx.x;
    const int t = threadIdx.x;
    int nz = (x[b * LSEQ + t] != 0) ? 1 : 0;
#pragma unroll
    for (int o = 32; o; o >>= 1) nz += __shfl_xor(nz, o, 64);
    __shared__ int red[4];
    if ((t & 63) == 0) red[t >> 6] = nz;
    __syncthreads();
    const int size = red[0] + red[1] + red[2] + red[3];
    mask[b * LSEQ + t] = (t < size) ? 1.0f : 0.0f;
}

// ---------------------------------------------------------------------------
// Gather + L2-normalize embedding rows into h[b,l,0:300] (row stride 600).
// One wave per row; 4 rows per block.
// ---------------------------------------------------------------------------
__global__ __launch_bounds__(256)
void gather_norm(const int* __restrict__ x, const float* __restrict__ emb,
                 float* __restrict__ h)
{
    const int t = threadIdx.x;
    const int lane = t & 63;
    const long long row = (long long)blockIdx.x * 4 + (t >> 6);
    const int tok = x[row];
    const float* er = emb + (long long)tok * EMBD;
    float vals[5];
    float ss = 0.f;
#pragma unroll
    for (int i = 0; i < 5; ++i) {
        const int c = lane + i * 64;
        const float v = (c < EMBD) ? er[c] : 0.f;
        vals[i] = v;
        ss = fmaf(v, v, ss);
    }
#pragma unroll
    for (int o = 32; o; o >>= 1) ss += __shfl_xor(ss, o, 64);
    const float inv = 1.0f / sqrtf(ss);
    float* out = h + row * 600;
#pragma unroll
    for (int i = 0; i < 5; ++i) {
        const int c = lane + i * 64;
        if (c < EMBD) out[c] = vals[i] * inv;
    }
}

// ---------------------------------------------------------------------------
// Row softmax over L=256 (one block of 256 threads per row), optional
// distance bias b_dist*( |i-j| >= 10 ) added before softmax.
// ---------------------------------------------------------------------------
template<bool DBIAS>
__global__ __launch_bounds__(256)
void row_softmax(const float* __restrict__ src, float* __restrict__ dst,
                 const float* __restrict__ b_dist)
{
    const long long row = blockIdx.x;
    const int i = (int)(row & (LSEQ - 1));
    const int t = threadIdx.x;
    float v = src[row * LSEQ + t];
    if (DBIAS) {
        const int d = (i > t) ? (i - t) : (t - i);
        if (d >= 10) v += b_dist[0];
    }
    float m = v;
#pragma unroll
    for (int o = 32; o; o >>= 1) m = fmaxf(m, __shfl_xor(m, o, 64));
    __shared__ float redm[4];
    if ((t & 63) == 0) redm[t >> 6] = m;
    __syncthreads();
    m = fmaxf(fmaxf(redm[0], redm[1]), fmaxf(redm[2], redm[3]));
    const float e = expf(v - m);
    float s = e;
#pragma unroll
    for (int o = 32; o; o >>= 1) s += __shfl_xor(s, o, 64);
    __shared__ float reds[4];
    if ((t & 63) == 0) reds[t >> 6] = s;
    __syncthreads();
    s = reds[0] + reds[1] + reds[2] + reds[3];
    dst[row * LSEQ + t] = e / s;
}

// ---------------------------------------------------------------------------
// Batched 256x256 transpose: out[b][i][k] = in[b][k][i]
// ---------------------------------------------------------------------------
__global__ __launch_bounds__(256)
void transpose256(const float* __restrict__ in, float* __restrict__ out)
{
    __shared__ float tile[32][33];
    const int b = blockIdx.z;
    const int i0 = blockIdx.x * 32;
    const int k0 = blockIdx.y * 32;
    const int tx = threadIdx.x & 31;
    const int ty = threadIdx.x >> 5;   // 0..7
    const float* ib = in + (long long)b * LSEQ * LSEQ;
    float* ob = out + (long long)b * LSEQ * LSEQ;
#pragma unroll
    for (int r = 0; r < 32; r += 8)
        tile[ty + r][tx] = ib[(long long)(k0 + ty + r) * LSEQ + i0 + tx];
    __syncthreads();
#pragma unroll
    for (int r = 0; r < 32; r += 8)
        ob[(long long)(i0 + ty + r) * LSEQ + k0 + tx] = tile[tx][ty + r];
}

// ---------------------------------------------------------------------------
// pooled[b][side*400 + c] = sum_l mask[b][l] * v[b][l][c]   (c < 400)
// ---------------------------------------------------------------------------
__global__ __launch_bounds__(256)
void masked_pool(const float* __restrict__ v, const float* __restrict__ mask,
                 float* __restrict__ pooled, int side)
{
    const int b = blockIdx.x;
    const int t = threadIdx.x;
    const float* vb = v + (long long)b * LSEQ * 400;
    const float* mb = mask + b * LSEQ;
    for (int c = t; c < 400; c += 256) {
        float s = 0.f;
        for (int l = 0; l < LSEQ; ++l)
            s = fmaf(vb[(long long)l * 400 + c], mb[l], s);
        pooled[(long long)b * 800 + side * 400 + c] = s;
    }
}

// ---------------------------------------------------------------------------
// out[b][c] = pooled[b][:800] . Wg[:,c] + bg[c]   (Wg row-major [800,3])
// ---------------------------------------------------------------------------
__global__ __launch_bounds__(256)
void final_fc(const float* __restrict__ pooled, const float* __restrict__ Wg,
              const float* __restrict__ bg, float* __restrict__ out)
{
    const int b = blockIdx.x;
    const int t = threadIdx.x;
    float a0 = 0.f, a1 = 0.f, a2 = 0.f;
    for (int k = t; k < 800; k += 256) {
        const float p = pooled[(long long)b * 800 + k];
        a0 = fmaf(p, Wg[k * 3 + 0], a0);
        a1 = fmaf(p, Wg[k * 3 + 1], a1);
        a2 = fmaf(p, Wg[k * 3 + 2], a2);
    }
#pragma unroll
    for (int o = 32; o; o >>= 1) {
        a0 += __shfl_xor(a0, o, 64);
        a1 += __shfl_xor(a1, o, 64);
        a2 += __shfl_xor(a2, o, 64);
    }
    __shared__ float r0[4], r1[4], r2[4];
    if ((t & 63) == 0) { r0[t >> 6] = a0; r1[t >> 6] = a1; r2[t >> 6] = a2; }
    __syncthreads();
    if (t == 0) {
        out[b * 3 + 0] = r0[0] + r0[1] + r0[2] + r0[3] + bg[0];
        out[b * 3 + 1] = r1[0] + r1[1] + r1[2] + r1[3] + bg[1];
        out[b * 3 + 2] = r2[0] + r2[1] + r2[2] + r2[3] + bg[2];
    }
}

// ---------------------------------------------------------------------------
extern "C" void kernel_launch(void* const* d_in, const int* in_sizes, int n_in,
                              void* d_out, int out_size, void* d_ws, size_t ws_size,
                              hipStream_t stream)
{
    (void)in_sizes; (void)n_in; (void)out_size; (void)ws_size;

    const int*   x1     = (const int*)  d_in[0];
    const int*   x2     = (const int*)  d_in[1];
    const float* emb    = (const float*)d_in[2];
    const float* Wi     = (const float*)d_in[3];
    const float* bi     = (const float*)d_in[4];
    const float* b_dist = (const float*)d_in[5];
    const float* Wp     = (const float*)d_in[6];
    const float* bp     = (const float*)d_in[7];
    const float* Wa     = (const float*)d_in[8];
    const float* ba     = (const float*)d_in[9];
    const float* Wc     = (const float*)d_in[10];
    const float* bc     = (const float*)d_in[11];
    const float* Wg     = (const float*)d_in[12];
    const float* bg     = (const float*)d_in[13];
    float* out = (float*)d_out;

    // ---- workspace layout (floats) ------------------------------------
    // H    : [B,L,600] h = [e | xp]            19,660,800 f  (later: sim | St/SR | v)
    // F    : [B,L,200] f / a1 / beta            6,553,600 f
    // S    : [B,L,256] att/S / a2 / alpha       8,388,608 f
    // P1,P2: [B,L,200]                          6,553,600 f each
    // POOL : [B,800], M1/M2: [B,L]
    float* ws   = (float*)d_ws;
    float* H    = ws;
    float* F    = ws + 19660800;
    float* S    = ws + 26214400;
    float* P1   = ws + 34603008;
    float* P2   = ws + 41156608;
    float* POOL = ws + 47710208;
    float* M1f  = ws + 47812608;
    float* M2f  = ws + 47845376;
    float* SIM  = H;                 // [B,256,256] after stage A
    float* SS   = H + 8388608;       // row-softmax / transposed col-softmax
    float* V    = H;                 // [B,L,400] compare output (after sim dead)

    const int ML = NB * LSEQ;        // 32768

    // masks
    make_mask<<<NB, 256, 0, stream>>>(x1, M1f);
    make_mask<<<NB, 256, 0, stream>>>(x2, M2f);

    // ---- stage A: per side -> P (projection) ---------------------------
    for (int s = 0; s < 2; ++s) {
        const int* xs = s ? x2 : x1;
        float* P = s ? P2 : P1;
        gather_norm<<<ML / 4, 256, 0, stream>>>(xs, emb, H);
        // f = relu(e @ Wi + bi)   [ML,300]x[300,200]
        gemm64<false, true, true, false, false><<<dim3(4, 512, 1), 256, 0, stream>>>(
            H, 600, 0, Wi, PRJ, 0, F, PRJ, 0, bi, nullptr, nullptr, ML, PRJ, EMBD);
        // att = f @ f^T  (batched 256x256, K=200)
        gemm64<true, false, false, false, false><<<dim3(4, 4, NB), 256, 0, stream>>>(
            F, PRJ, 51200, F, PRJ, 51200, S, LSEQ, 65536, nullptr, nullptr, nullptr,
            LSEQ, LSEQ, PRJ);
        // softmax rows with distance bias (in place)
        row_softmax<true><<<ML, 256, 0, stream>>>(S, S, b_dist);
        // xp = S @ e  -> h[:,300:600]
        gemm64<false, false, false, false, false><<<dim3(5, 4, NB), 256, 0, stream>>>(
            S, LSEQ, 65536, H, 600, 153600, H + 300, 600, 153600, nullptr, nullptr, nullptr,
            LSEQ, EMBD, LSEQ);
        // P = h @ Wp + bp   [ML,600]x[600,200]
        gemm64<false, true, false, false, false><<<dim3(4, 512, 1), 256, 0, stream>>>(
            H, 600, 0, Wp, PRJ, 0, P, PRJ, 0, bp, nullptr, nullptr, ML, PRJ, 600);
    }

    // ---- stage B: cross attention --------------------------------------
    // a1 = relu(P1 @ Wa + ba), a2 = relu(P2 @ Wa + ba)
    gemm64<false, true, true, false, false><<<dim3(4, 512, 1), 256, 0, stream>>>(
        P1, PRJ, 0, Wa, PRJ, 0, F, PRJ, 0, ba, nullptr, nullptr, ML, PRJ, PRJ);
    gemm64<false, true, true, false, false><<<dim3(4, 512, 1), 256, 0, stream>>>(
        P2, PRJ, 0, Wa, PRJ, 0, S, PRJ, 0, ba, nullptr, nullptr, ML, PRJ, PRJ);
    // sim = (a1 @ a2^T) * mask1[i] * mask2[j]
    gemm64<true, false, false, false, true><<<dim3(4, 4, NB), 256, 0, stream>>>(
        F, PRJ, 51200, S, PRJ, 51200, SIM, LSEQ, 65536, nullptr, M1f, M2f,
        LSEQ, LSEQ, PRJ);
    // beta = rowsoftmax(sim) @ P2
    row_softmax<false><<<ML, 256, 0, stream>>>(SIM, SS, nullptr);
    gemm64<false, false, false, false, false><<<dim3(4, 4, NB), 256, 0, stream>>>(
        SS, LSEQ, 65536, P2, PRJ, 51200, F, PRJ, 51200, nullptr, nullptr, nullptr,
        LSEQ, PRJ, LSEQ);
    // alpha = colsoftmax(sim)^T @ P1 == rowsoftmax(sim^T) @ P1
    transpose256<<<dim3(8, 8, NB), 256, 0, stream>>>(SIM, SS);
    row_softmax<false><<<ML, 256, 0, stream>>>(SS, SS, nullptr);
    gemm64<false, false, false, false, false><<<dim3(4, 4, NB), 256, 0, stream>>>(
        SS, LSEQ, 65536, P1, PRJ, 51200, S, PRJ, 51200, nullptr, nullptr, nullptr,
        LSEQ, PRJ, LSEQ);

    // ---- compare + pool -------------------------------------------------
    // v1 = relu(P1 @ Wc[0:200] + beta @ Wc[200:400] + bc)
    gemm64<false, false, false, false, false><<<dim3(7, 512, 1), 256, 0, stream>>>(
        P1, PRJ, 0, Wc, 400, 0, V, 400, 0, nullptr, nullptr, nullptr, ML, 400, PRJ);
    gemm64<false, true, true, true, false><<<dim3(7, 512, 1), 256, 0, stream>>>(
        F, PRJ, 0, Wc + 200 * 400, 400, 0, V, 400, 0, bc, nullptr, nullptr, ML, 400, PRJ);
    masked_pool<<<NB, 256, 0, stream>>>(V, M1f, POOL, 0);
    // v2 = relu(P2 @ Wc[0:200] + alpha @ Wc[200:400] + bc)
    gemm64<false, false, false, false, false><<<dim3(7, 512, 1), 256, 0, stream>>>(
        P2, PRJ, 0, Wc, 400, 0, V, 400, 0, nullptr, nullptr, nullptr, ML, 400, PRJ);
    gemm64<false, true, true, true, false><<<dim3(7, 512, 1), 256, 0, stream>>>(
        S, PRJ, 0, Wc + 200 * 400, 400, 0, V, 400, 0, bc, nullptr, nullptr, ML, 400, PRJ);
    masked_pool<<<NB, 256, 0, stream>>>(V, M2f, POOL, 1);

    // ---- classifier ------------------------------------------------------
    final_fc<<<NB, 256, 0, stream>>>(POOL, Wg, bg, out);
}

// Round 2
// 904.619 us; speedup vs baseline: 1.7751x; 1.7751x over previous
//
#include <hip/hip_runtime.h>
#include <math.h>

// Problem dims
#define LSEQ 256
#define NB   128
#define EMBD 300
#define PRJ  200

typedef unsigned short u16;
typedef unsigned int   u32;
typedef __attribute__((ext_vector_type(8))) short bf16x8;  // 8 bf16 = 4 VGPR
typedef __attribute__((ext_vector_type(4))) float f32x4;

#define BK     32
#define APITCH 40   // 32 + 8 pad (80 B row = 20 banks -> 2-way, free)

static __device__ inline u16 f2bf(float x) {
    union { float f; u32 u; } v; v.f = x;
    const u32 r = v.u + 0x7fffu + ((v.u >> 16) & 1u);   // RNE
    return (u16)(r >> 16);
}

// ---------------------------------------------------------------------------
// bf16-MFMA tiled GEMM: C[bz] = act(A[bz] @ op(B[bz]) [+C_old] [+bias]) [*mask]
// A row-major MxK (f32). B row-major KxN (TB=false) or NxK (TB=true), f32.
// 128x128 tile, BK=32, 256 threads = 4 waves (2x2), each wave 64x64 = 4x4
// fragments of v_mfma_f32_16x16x32_bf16. f32->bf16 conversion in staging.
// Requires M % 128 == 0 (true for all call sites; guarded anyway).
// ---------------------------------------------------------------------------
template<bool TB, bool BIAS, bool RELU, bool ACC, bool MASKE>
__global__ __launch_bounds__(256)
void gemm_mfma(const float* __restrict__ A, int lda, long long sA,
               const float* __restrict__ B, int ldb, long long sB,
               float* __restrict__ C, int ldc, long long sC,
               const float* __restrict__ bias,
               const float* __restrict__ m1, const float* __restrict__ m2,
               int M, int N, int K)
{
    __shared__ u16 As[128 * APITCH];
    __shared__ u16 Bs[128 * APITCH];

    const int bz = blockIdx.z;
    const float* Ab = A + (long long)bz * sA;
    const float* Bb = B + (long long)bz * sB;
    float* Cb = C + (long long)bz * sC;

    const int m0 = blockIdx.y * 128;
    const int n0 = blockIdx.x * 128;
    const int t  = threadIdx.x;
    const int lane = t & 63;
    const int w    = t >> 6;
    const int wm   = w >> 1;       // 0..1
    const int wn   = w & 1;        // 0..1
    const int lr   = lane & 15;    // row/col within 16x16 fragment
    const int lk   = (lane >> 4) << 3;  // k offset 0,8,16,24 (ushorts)

    f32x4 acc[4][4] = {};

    for (int k0 = 0; k0 < K; k0 += BK) {
        // ---- stage A: As[m][k], thread t -> row t>>1, half-row (t&1)*16
        {
            const int m  = t >> 1;
            const int kh = (t & 1) << 4;
            const long long gm = (long long)m0 + m;
            const int gk = k0 + kh;
            float v[16];
            if (gm < M) {
                const float* src = Ab + gm * (long long)lda + gk;
                if (gk + 15 < K) {
#pragma unroll
                    for (int i = 0; i < 16; i += 4) {
                        const float4 f = *reinterpret_cast<const float4*>(src + i);
                        v[i] = f.x; v[i+1] = f.y; v[i+2] = f.z; v[i+3] = f.w;
                    }
                } else {
#pragma unroll
                    for (int i = 0; i < 16; ++i) v[i] = (gk + i < K) ? src[i] : 0.f;
                }
            } else {
#pragma unroll
                for (int i = 0; i < 16; ++i) v[i] = 0.f;
            }
            u32 u[8];
#pragma unroll
            for (int i = 0; i < 8; ++i)
                u[i] = (u32)f2bf(v[2*i]) | ((u32)f2bf(v[2*i+1]) << 16);
            u32* dst = reinterpret_cast<u32*>(&As[m * APITCH + kh]);
            *reinterpret_cast<uint4*>(dst)     = make_uint4(u[0], u[1], u[2], u[3]);
            *reinterpret_cast<uint4*>(dst + 4) = make_uint4(u[4], u[5], u[6], u[7]);
        }
        // ---- stage B: Bs[n][k]
        if (TB) {
            const int n  = t >> 1;
            const int kh = (t & 1) << 4;
            const long long gn = (long long)n0 + n;
            const int gk = k0 + kh;
            float v[16];
            if (gn < N) {
                const float* src = Bb + gn * (long long)ldb + gk;
                if (gk + 15 < K) {
#pragma unroll
                    for (int i = 0; i < 16; i += 4) {
                        const float4 f = *reinterpret_cast<const float4*>(src + i);
                        v[i] = f.x; v[i+1] = f.y; v[i+2] = f.z; v[i+3] = f.w;
                    }
                } else {
#pragma unroll
                    for (int i = 0; i < 16; ++i) v[i] = (gk + i < K) ? src[i] : 0.f;
                }
            } else {
#pragma unroll
                for (int i = 0; i < 16; ++i) v[i] = 0.f;
            }
            u32 u[8];
#pragma unroll
            for (int i = 0; i < 8; ++i)
                u[i] = (u32)f2bf(v[2*i]) | ((u32)f2bf(v[2*i+1]) << 16);
            u32* dst = reinterpret_cast<u32*>(&Bs[n * APITCH + kh]);
            *reinterpret_cast<uint4*>(dst)     = make_uint4(u[0], u[1], u[2], u[3]);
            *reinterpret_cast<uint4*>(dst + 4) = make_uint4(u[4], u[5], u[6], u[7]);
        } else {
            // B is KxN: load 4k x 4n micro-tile, transpose into Bs[n][k]
            const int n4 = (t & 31) << 2;   // 0..124
            const int k4 = (t >> 5) << 2;   // 0..28
            const long long gn = (long long)n0 + n4;
            float r[4][4];
#pragma unroll
            for (int i = 0; i < 4; ++i) {
                const int gk = k0 + k4 + i;
                if (gk < K) {
                    const float* src = Bb + (long long)gk * ldb + gn;
                    if (gn + 3 < N) {
                        const float4 f = *reinterpret_cast<const float4*>(src);
                        r[i][0] = f.x; r[i][1] = f.y; r[i][2] = f.z; r[i][3] = f.w;
                    } else {
#pragma unroll
                        for (int j = 0; j < 4; ++j) r[i][j] = (gn + j < N) ? src[j] : 0.f;
                    }
                } else {
                    r[i][0] = r[i][1] = r[i][2] = r[i][3] = 0.f;
                }
            }
#pragma unroll
            for (int j = 0; j < 4; ++j) {
                const u32 lo = (u32)f2bf(r[0][j]) | ((u32)f2bf(r[1][j]) << 16);
                const u32 hi = (u32)f2bf(r[2][j]) | ((u32)f2bf(r[3][j]) << 16);
                *reinterpret_cast<uint2*>(&Bs[(n4 + j) * APITCH + k4]) = make_uint2(lo, hi);
            }
        }
        __syncthreads();

        // ---- fragments + MFMA
        bf16x8 af[4], bfr[4];
#pragma unroll
        for (int mi = 0; mi < 4; ++mi)
            af[mi] = *reinterpret_cast<const bf16x8*>(&As[(wm*64 + mi*16 + lr) * APITCH + lk]);
#pragma unroll
        for (int ni = 0; ni < 4; ++ni)
            bfr[ni] = *reinterpret_cast<const bf16x8*>(&Bs[(wn*64 + ni*16 + lr) * APITCH + lk]);
#pragma unroll
        for (int mi = 0; mi < 4; ++mi)
#pragma unroll
            for (int ni = 0; ni < 4; ++ni)
                acc[mi][ni] = __builtin_amdgcn_mfma_f32_16x16x32_bf16(
                    af[mi], bfr[ni], acc[mi][ni], 0, 0, 0);
        __syncthreads();
    }

    // ---- epilogue: C/D layout col=lane&15, row=(lane>>4)*4+reg
    const int rbase = (lane >> 4) << 2;
#pragma unroll
    for (int mi = 0; mi < 4; ++mi) {
#pragma unroll
        for (int ni = 0; ni < 4; ++ni) {
            const int gc = n0 + wn*64 + ni*16 + lr;
            if (gc >= N) continue;
            const int gr0 = m0 + wm*64 + mi*16 + rbase;
#pragma unroll
            for (int r = 0; r < 4; ++r) {
                const long long gr = gr0 + r;
                if (gr >= M) continue;
                float x = acc[mi][ni][r];
                if (ACC)  x += Cb[gr * ldc + gc];
                if (BIAS) x += bias[gc];
                if (RELU) x = fmaxf(x, 0.f);
                if (MASKE) x *= m1[(long long)bz * M + gr] * m2[(long long)bz * N + gc];
                Cb[gr * ldc + gc] = x;
            }
        }
    }
}

// ---------------------------------------------------------------------------
// mask[b][l] = (l < count_nonzero(x[b,:])) ? 1 : 0
// ---------------------------------------------------------------------------
__global__ __launch_bounds__(256)
void make_mask(const int* __restrict__ x, float* __restrict__ mask)
{
    const int b = blockIdx.x;
    const int t = threadIdx.x;
    int nz = (x[b * LSEQ + t] != 0) ? 1 : 0;
#pragma unroll
    for (int o = 32; o; o >>= 1) nz += __shfl_xor(nz, o, 64);
    __shared__ int red[4];
    if ((t & 63) == 0) red[t >> 6] = nz;
    __syncthreads();
    const int size = red[0] + red[1] + red[2] + red[3];
    mask[b * LSEQ + t] = (t < size) ? 1.0f : 0.0f;
}

// ---------------------------------------------------------------------------
// Gather + L2-normalize embedding rows into h[b,l,0:300] (row stride 600).
// ---------------------------------------------------------------------------
__global__ __launch_bounds__(256)
void gather_norm(const int* __restrict__ x, const float* __restrict__ emb,
                 float* __restrict__ h)
{
    const int t = threadIdx.x;
    const int lane = t & 63;
    const long long row = (long long)blockIdx.x * 4 + (t >> 6);
    const int tok = x[row];
    const float* er = emb + (long long)tok * EMBD;
    float vals[5];
    float ss = 0.f;
#pragma unroll
    for (int i = 0; i < 5; ++i) {
        const int c = lane + i * 64;
        const float v = (c < EMBD) ? er[c] : 0.f;
        vals[i] = v;
        ss = fmaf(v, v, ss);
    }
#pragma unroll
    for (int o = 32; o; o >>= 1) ss += __shfl_xor(ss, o, 64);
    const float inv = 1.0f / sqrtf(ss);
    float* out = h + row * 600;
#pragma unroll
    for (int i = 0; i < 5; ++i) {
        const int c = lane + i * 64;
        if (c < EMBD) out[c] = vals[i] * inv;
    }
}

// ---------------------------------------------------------------------------
// Row softmax over L=256, optional distance bias b_dist*(|i-j|>=10).
// ---------------------------------------------------------------------------
template<bool DBIAS>
__global__ __launch_bounds__(256)
void row_softmax(const float* __restrict__ src, float* __restrict__ dst,
                 const float* __restrict__ b_dist)
{
    const long long row = blockIdx.x;
    const int i = (int)(row & (LSEQ - 1));
    const int t = threadIdx.x;
    float v = src[row * LSEQ + t];
    if (DBIAS) {
        const int d = (i > t) ? (i - t) : (t - i);
        if (d >= 10) v += b_dist[0];
    }
    float m = v;
#pragma unroll
    for (int o = 32; o; o >>= 1) m = fmaxf(m, __shfl_xor(m, o, 64));
    __shared__ float redm[4];
    if ((t & 63) == 0) redm[t >> 6] = m;
    __syncthreads();
    m = fmaxf(fmaxf(redm[0], redm[1]), fmaxf(redm[2], redm[3]));
    const float e = expf(v - m);
    float s = e;
#pragma unroll
    for (int o = 32; o; o >>= 1) s += __shfl_xor(s, o, 64);
    __shared__ float reds[4];
    if ((t & 63) == 0) reds[t >> 6] = s;
    __syncthreads();
    s = reds[0] + reds[1] + reds[2] + reds[3];
    dst[row * LSEQ + t] = e / s;
}

// ---------------------------------------------------------------------------
// Batched 256x256 transpose
// ---------------------------------------------------------------------------
__global__ __launch_bounds__(256)
void transpose256(const float* __restrict__ in, float* __restrict__ out)
{
    __shared__ float tile[32][33];
    const int b = blockIdx.z;
    const int i0 = blockIdx.x * 32;
    const int k0 = blockIdx.y * 32;
    const int tx = threadIdx.x & 31;
    const int ty = threadIdx.x >> 5;
    const float* ib = in + (long long)b * LSEQ * LSEQ;
    float* ob = out + (long long)b * LSEQ * LSEQ;
#pragma unroll
    for (int r = 0; r < 32; r += 8)
        tile[ty + r][tx] = ib[(long long)(k0 + ty + r) * LSEQ + i0 + tx];
    __syncthreads();
#pragma unroll
    for (int r = 0; r < 32; r += 8)
        ob[(long long)(i0 + ty + r) * LSEQ + k0 + tx] = tile[tx][ty + r];
}

// ---------------------------------------------------------------------------
// pooled[b][side*400 + c] = sum_l mask[b][l] * v[b][l][c]
// ---------------------------------------------------------------------------
__global__ __launch_bounds__(256)
void masked_pool(const float* __restrict__ v, const float* __restrict__ mask,
                 float* __restrict__ pooled, int side)
{
    const int b = blockIdx.x;
    const int t = threadIdx.x;
    const float* vb = v + (long long)b * LSEQ * 400;
    const float* mb = mask + b * LSEQ;
    for (int c = t; c < 400; c += 256) {
        float s = 0.f;
        for (int l = 0; l < LSEQ; ++l)
            s = fmaf(vb[(long long)l * 400 + c], mb[l], s);
        pooled[(long long)b * 800 + side * 400 + c] = s;
    }
}

// ---------------------------------------------------------------------------
__global__ __launch_bounds__(256)
void final_fc(const float* __restrict__ pooled, const float* __restrict__ Wg,
              const float* __restrict__ bg, float* __restrict__ out)
{
    const int b = blockIdx.x;
    const int t = threadIdx.x;
    float a0 = 0.f, a1 = 0.f, a2 = 0.f;
    for (int k = t; k < 800; k += 256) {
        const float p = pooled[(long long)b * 800 + k];
        a0 = fmaf(p, Wg[k * 3 + 0], a0);
        a1 = fmaf(p, Wg[k * 3 + 1], a1);
        a2 = fmaf(p, Wg[k * 3 + 2], a2);
    }
#pragma unroll
    for (int o = 32; o; o >>= 1) {
        a0 += __shfl_xor(a0, o, 64);
        a1 += __shfl_xor(a1, o, 64);
        a2 += __shfl_xor(a2, o, 64);
    }
    __shared__ float r0[4], r1[4], r2[4];
    if ((t & 63) == 0) { r0[t >> 6] = a0; r1[t >> 6] = a1; r2[t >> 6] = a2; }
    __syncthreads();
    if (t == 0) {
        out[b * 3 + 0] = r0[0] + r0[1] + r0[2] + r0[3] + bg[0];
        out[b * 3 + 1] = r1[0] + r1[1] + r1[2] + r1[3] + bg[1];
        out[b * 3 + 2] = r2[0] + r2[1] + r2[2] + r2[3] + bg[2];
    }
}

// ---------------------------------------------------------------------------
extern "C" void kernel_launch(void* const* d_in, const int* in_sizes, int n_in,
                              void* d_out, int out_size, void* d_ws, size_t ws_size,
                              hipStream_t stream)
{
    (void)in_sizes; (void)n_in; (void)out_size; (void)ws_size;

    const int*   x1     = (const int*)  d_in[0];
    const int*   x2     = (const int*)  d_in[1];
    const float* emb    = (const float*)d_in[2];
    const float* Wi     = (const float*)d_in[3];
    const float* bi     = (const float*)d_in[4];
    const float* b_dist = (const float*)d_in[5];
    const float* Wp     = (const float*)d_in[6];
    const float* bp     = (const float*)d_in[7];
    const float* Wa     = (const float*)d_in[8];
    const float* ba     = (const float*)d_in[9];
    const float* Wc     = (const float*)d_in[10];
    const float* bc     = (const float*)d_in[11];
    const float* Wg     = (const float*)d_in[12];
    const float* bg     = (const float*)d_in[13];
    float* out = (float*)d_out;

    // ---- workspace layout (floats), 191.5 MB total (proven size) -------
    float* ws   = (float*)d_ws;
    float* H    = ws;                 // [ML,600]; stage B: SIM+SS; then V
    float* F    = ws + 19660800;      // [ML,200] f / a1 / beta
    float* ATT  = ws + 26214400;      // [B,256,256] att; a2; alpha
    float* P1   = ws + 34603008;      // [ML,200]
    float* P2   = ws + 41156608;      // [ML,200]
    float* POOL = ws + 47710208;      // [B,800]
    float* M1f  = ws + 47812608;      // [B,256]
    float* M2f  = ws + 47845376;      // [B,256]
    float* SIM  = H;                  // [B,256,256]
    float* SS   = H + 8388608;        // [B,256,256]
    float* V    = H;                  // [ML,400] compare output

    const int ML = NB * LSEQ;         // 32768

    make_mask<<<NB, 256, 0, stream>>>(x1, M1f);
    make_mask<<<NB, 256, 0, stream>>>(x2, M2f);

    // ---- stage A: per side -> P ----------------------------------------
    for (int s = 0; s < 2; ++s) {
        const int* xs = s ? x2 : x1;
        float* P = s ? P2 : P1;
        gather_norm<<<ML / 4, 256, 0, stream>>>(xs, emb, H);
        // f = relu(e @ Wi + bi)   [ML,300]x[300,200]
        gemm_mfma<false, true, true, false, false><<<dim3(2, 256, 1), 256, 0, stream>>>(
            H, 600, 0, Wi, PRJ, 0, F, PRJ, 0, bi, nullptr, nullptr, ML, PRJ, EMBD);
        // att = f @ f^T (batched, K=200)
        gemm_mfma<true, false, false, false, false><<<dim3(2, 2, NB), 256, 0, stream>>>(
            F, PRJ, 51200, F, PRJ, 51200, ATT, LSEQ, 65536, nullptr, nullptr, nullptr,
            LSEQ, LSEQ, PRJ);
        row_softmax<true><<<ML, 256, 0, stream>>>(ATT, ATT, b_dist);
        // xp = softmax(att) @ e -> h[:,300:600]
        gemm_mfma<false, false, false, false, false><<<dim3(3, 2, NB), 256, 0, stream>>>(
            ATT, LSEQ, 65536, H, 600, 153600, H + 300, 600, 153600, nullptr, nullptr, nullptr,
            LSEQ, EMBD, LSEQ);
        // P = h @ Wp + bp   [ML,600]x[600,200]
        gemm_mfma<false, true, false, false, false><<<dim3(2, 256, 1), 256, 0, stream>>>(
            H, 600, 0, Wp, PRJ, 0, P, PRJ, 0, bp, nullptr, nullptr, ML, PRJ, 600);
    }

    // ---- stage B: cross attention ---------------------------------------
    gemm_mfma<false, true, true, false, false><<<dim3(2, 256, 1), 256, 0, stream>>>(
        P1, PRJ, 0, Wa, PRJ, 0, F, PRJ, 0, ba, nullptr, nullptr, ML, PRJ, PRJ);
    gemm_mfma<false, true, true, false, false><<<dim3(2, 256, 1), 256, 0, stream>>>(
        P2, PRJ, 0, Wa, PRJ, 0, ATT, PRJ, 0, ba, nullptr, nullptr, ML, PRJ, PRJ);
    // sim = (a1 @ a2^T) * mask1[i] * mask2[j]
    gemm_mfma<true, false, false, false, true><<<dim3(2, 2, NB), 256, 0, stream>>>(
        F, PRJ, 51200, ATT, PRJ, 51200, SIM, LSEQ, 65536, nullptr, M1f, M2f,
        LSEQ, LSEQ, PRJ);
    // beta = rowsoftmax(sim) @ P2  -> F
    row_softmax<false><<<ML, 256, 0, stream>>>(SIM, SS, nullptr);
    gemm_mfma<false, false, false, false, false><<<dim3(2, 2, NB), 256, 0, stream>>>(
        SS, LSEQ, 65536, P2, PRJ, 51200, F, PRJ, 51200, nullptr, nullptr, nullptr,
        LSEQ, PRJ, LSEQ);
    // alpha = rowsoftmax(sim^T) @ P1 -> ATT
    transpose256<<<dim3(8, 8, NB), 256, 0, stream>>>(SIM, SS);
    row_softmax<false><<<ML, 256, 0, stream>>>(SS, SS, nullptr);
    gemm_mfma<false, false, false, false, false><<<dim3(2, 2, NB), 256, 0, stream>>>(
        SS, LSEQ, 65536, P1, PRJ, 51200, ATT, PRJ, 51200, nullptr, nullptr, nullptr,
        LSEQ, PRJ, LSEQ);

    // ---- compare + pool ---------------------------------------------------
    // v1 = relu(P1 @ Wc[0:200] + beta @ Wc[200:400] + bc)
    gemm_mfma<false, false, false, false, false><<<dim3(4, 256, 1), 256, 0, stream>>>(
        P1, PRJ, 0, Wc, 400, 0, V, 400, 0, nullptr, nullptr, nullptr, ML, 400, PRJ);
    gemm_mfma<false, true, true, true, false><<<dim3(4, 256, 1), 256, 0, stream>>>(
        F, PRJ, 0, Wc + 200 * 400, 400, 0, V, 400, 0, bc, nullptr, nullptr, ML, 400, PRJ);
    masked_pool<<<NB, 256, 0, stream>>>(V, M1f, POOL, 0);
    // v2 = relu(P2 @ Wc[0:200] + alpha @ Wc[200:400] + bc)
    gemm_mfma<false, false, false, false, false><<<dim3(4, 256, 1), 256, 0, stream>>>(
        P2, PRJ, 0, Wc, 400, 0, V, 400, 0, nullptr, nullptr, nullptr, ML, 400, PRJ);
    gemm_mfma<false, true, true, true, false><<<dim3(4, 256, 1), 256, 0, stream>>>(
        ATT, PRJ, 0, Wc + 200 * 400, 400, 0, V, 400, 0, bc, nullptr, nullptr, ML, 400, PRJ);
    masked_pool<<<NB, 256, 0, stream>>>(V, M2f, POOL, 1);

    final_fc<<<NB, 256, 0, stream>>>(POOL, Wg, bg, out);
}

// Round 3
// 423.432 us; speedup vs baseline: 3.7922x; 2.1364x over previous
//
#include <hip/hip_runtime.h>
#include <math.h>

#define LSEQ 256
#define NB   128

typedef unsigned short u16;
typedef unsigned int   u32;
typedef __attribute__((ext_vector_type(8))) short bf16x8;  // 8 bf16 = 4 VGPR
typedef __attribute__((ext_vector_type(4))) float f32x4;

static __device__ __forceinline__ u16 f2bf(float x) {
    union { float f; u32 u; } v; v.f = x;
    const u32 r = v.u + 0x7fffu + ((v.u >> 16) & 1u);   // RNE
    return (u16)(r >> 16);
}
static __device__ __forceinline__ float bf2f(u16 u) {
    union { u32 i; float f; } v; v.i = ((u32)u) << 16; return v.f;
}
// async global->LDS, 16B per lane, dest = wave-uniform base + lane*16
static __device__ __forceinline__ void glds16(const u16* src, u16* dst) {
    __builtin_amdgcn_global_load_lds(
        (const __attribute__((address_space(1))) u32*)src,
        (__attribute__((address_space(3))) u32*)dst, 16, 0, 0);
}

// ---------------------------------------------------------------------------
// bf16 MFMA GEMM. Block = 128 rows x 256 cols, 512 threads = 8 waves (2x4),
// wave tile 64x64 (4x4 fragments of 16x16x32). BK=64.
// A: bf16 row-major MxK (lda, K mult of 64, padded buffers). glds-staged.
// B: BMODE 0 -> bf16 [N][K] (TB), glds-staged. BMODE 1 -> bf16 [K][N],
//    reg-transpose staged, cols >= Bn read as 0.
// LDS: linear rows of 128B, 8 slots of 16B, XOR-swizzle slot ^= (row&7)
// applied on BOTH stage-source and read (involution, rule #21).
// Epilogue: bias (gc<Nbias), relu, mask (batched), or fused masked row-pool.
// ---------------------------------------------------------------------------
template<int BMODE, bool BIAS, bool RELU, bool MASKE, bool POOLE, bool BATCHED>
__global__ __launch_bounds__(512)
void gemm(const u16* __restrict__ A, int lda, long long sA,
          const u16* __restrict__ B, int ldb, long long sB,
          u16* __restrict__ C, int ldc, long long sC,
          const float* __restrict__ bias, int Nbias,
          const float* __restrict__ m1, const float* __restrict__ m2,
          float* __restrict__ pool, int poolOff, const float* __restrict__ pmask,
          int K, int Bn, int Nwrite)
{
    __shared__ u16 As[128 * 64];   // 16 KB
    __shared__ u16 Bs[256 * 64];   // 32 KB

    const int bz = BATCHED ? blockIdx.z : 0;
    const u16* Ab = A + (long long)bz * sA;
    const u16* Bb = B + (long long)bz * sB;
    const int m0 = blockIdx.y * 128;
    const int n0 = blockIdx.x * 256;
    const int t = threadIdx.x;
    const int lane = t & 63;
    const int w = t >> 6;          // 0..7
    const int wm = w >> 2;         // 0..1
    const int wn = w & 3;          // 0..3
    const int lr = lane & 15;
    const int lg = lane >> 4;      // 0..3

    f32x4 acc[4][4] = {};

    for (int k0 = 0; k0 < K; k0 += 64) {
        // ---- stage A: 16 KB = 16 chunks of 1KB; wave w -> chunks 2w,2w+1
#pragma unroll
        for (int i = 0; i < 2; ++i) {
            const int ch = w * 2 + i;
            const int row = (ch << 3) + (lane >> 3);
            const int slot = (lane & 7) ^ (row & 7);
            glds16(Ab + (long long)(m0 + row) * lda + k0 + (slot << 3),
                   &As[ch << 9]);
        }
        // ---- stage B
        if (BMODE == 0) {
#pragma unroll
            for (int i = 0; i < 4; ++i) {
                const int ch = w * 4 + i;
                const int row = (ch << 3) + (lane >> 3);
                const int slot = (lane & 7) ^ (row & 7);
                glds16(Bb + (long long)(n0 + row) * ldb + k0 + (slot << 3),
                       &Bs[ch << 9]);
            }
        } else {
            // B is [K][N]: thread covers 8k x 4n, transpose in regs
            const int n4 = (t & 63) << 2;    // 0..252
            const int k8 = w << 3;           // 0..56
            union { uint2 q2[8]; u16 s[32]; } uq;
#pragma unroll
            for (int i = 0; i < 8; ++i)
                uq.q2[i] = *reinterpret_cast<const uint2*>(
                    Bb + (long long)(k0 + k8 + i) * ldb + n0 + n4);
#pragma unroll
            for (int j = 0; j < 4; ++j) {
                u32 v0 = 0, v1 = 0, v2 = 0, v3 = 0;
                if (n0 + n4 + j < Bn) {
                    v0 = (u32)uq.s[j]      | ((u32)uq.s[4 + j]  << 16);
                    v1 = (u32)uq.s[8 + j]  | ((u32)uq.s[12 + j] << 16);
                    v2 = (u32)uq.s[16 + j] | ((u32)uq.s[20 + j] << 16);
                    v3 = (u32)uq.s[24 + j] | ((u32)uq.s[28 + j] << 16);
                }
                const int row = n4 + j;
                const int slot = w ^ (row & 7);
                *reinterpret_cast<uint4*>(&Bs[row * 64 + (slot << 3)]) =
                    make_uint4(v0, v1, v2, v3);
            }
        }
        __syncthreads();

        // ---- fragments + MFMA (2 k-halves of 32)
#pragma unroll
        for (int kk = 0; kk < 2; ++kk) {
            bf16x8 af[4], bf[4];
#pragma unroll
            for (int mi = 0; mi < 4; ++mi) {
                const int row = wm * 64 + mi * 16 + lr;
                const int slot = ((kk << 2) + lg) ^ (row & 7);
                af[mi] = *reinterpret_cast<const bf16x8*>(&As[row * 64 + (slot << 3)]);
            }
#pragma unroll
            for (int ni = 0; ni < 4; ++ni) {
                const int row = wn * 64 + ni * 16 + lr;
                const int slot = ((kk << 2) + lg) ^ (row & 7);
                bf[ni] = *reinterpret_cast<const bf16x8*>(&Bs[row * 64 + (slot << 3)]);
            }
#pragma unroll
            for (int mi = 0; mi < 4; ++mi)
#pragma unroll
                for (int ni = 0; ni < 4; ++ni)
                    acc[mi][ni] = __builtin_amdgcn_mfma_f32_16x16x32_bf16(
                        af[mi], bf[ni], acc[mi][ni], 0, 0, 0);
        }
        __syncthreads();
    }

    const int rbase = lg << 2;
    if (!POOLE) {
        u16* Cb = C + (long long)bz * sC;
        float m1v[4][4];
        if (MASKE) {
#pragma unroll
            for (int mi = 0; mi < 4; ++mi)
#pragma unroll
                for (int r = 0; r < 4; ++r)
                    m1v[mi][r] = m1[bz * 256 + m0 + wm * 64 + mi * 16 + rbase + r];
        }
#pragma unroll
        for (int ni = 0; ni < 4; ++ni) {
            const int gc = n0 + wn * 64 + ni * 16 + lr;
            if (gc >= Nwrite) continue;
            float bcv = 0.f;
            if (BIAS) bcv = (gc < Nbias) ? bias[gc] : 0.f;
            float m2v = 0.f;
            if (MASKE) m2v = m2[bz * 256 + gc];
#pragma unroll
            for (int mi = 0; mi < 4; ++mi) {
#pragma unroll
                for (int r = 0; r < 4; ++r) {
                    const long long gr = m0 + wm * 64 + mi * 16 + rbase + r;
                    float x = acc[mi][ni][r];
                    if (BIAS) x += bcv;
                    if (RELU) x = fmaxf(x, 0.f);
                    if (MASKE) x *= m1v[mi][r] * m2v;
                    Cb[gr * ldc + gc] = f2bf(x);
                }
            }
        }
    } else {
        // fused compare epilogue: pooled[b][poolOff+gc] += relu(acc+bc)*mask[row]
        __syncthreads();
        float* pool_s = reinterpret_cast<float*>(As);
        for (int i = t; i < 256; i += 512) pool_s[i] = 0.f;
        __syncthreads();
        const int b = m0 >> 8;
        const float* mk = pmask + b * 256 + (m0 & 255);
        float mrow[4][4];
#pragma unroll
        for (int mi = 0; mi < 4; ++mi)
#pragma unroll
            for (int r = 0; r < 4; ++r)
                mrow[mi][r] = mk[wm * 64 + mi * 16 + rbase + r];
#pragma unroll
        for (int ni = 0; ni < 4; ++ni) {
            const int lc = wn * 64 + ni * 16 + lr;
            const int gc = n0 + lc;
            const float bcv = (BIAS && gc < Nbias) ? bias[gc] : 0.f;
            float cs = 0.f;
#pragma unroll
            for (int mi = 0; mi < 4; ++mi)
#pragma unroll
                for (int r = 0; r < 4; ++r)
                    cs += fmaxf(acc[mi][ni][r] + bcv, 0.f) * mrow[mi][r];
            cs += __shfl_xor(cs, 16, 64);
            cs += __shfl_xor(cs, 32, 64);
            if (lg == 0) atomicAdd(&pool_s[lc], cs);
        }
        __syncthreads();
        for (int i = t; i < 256; i += 512) {
            const int gc = n0 + i;
            if (gc < Nwrite) atomicAdd(&pool[b * 800 + poolOff + gc], pool_s[i]);
        }
    }
}

// ---------------------------------------------------------------------------
// weight prep: dst[n][k] (bf16, [dstRows][dstCols]) = src[srcRow(k)][n] or 0.
// srcRow(k): k<seg1 -> k ; seg2start<=k<seg2start+(srcRows-seg1) -> seg1+(k-seg2start)
// ---------------------------------------------------------------------------
__global__ __launch_bounds__(256)
void prep_w(const float* __restrict__ src, int srcRows, int srcCols,
            u16* __restrict__ dst, int dstCols, int dstTotal,
            int seg1, int seg2start)
{
    const int idx = blockIdx.x * 256 + threadIdx.x;
    if (idx >= dstTotal) return;
    const int n = idx / dstCols, k = idx - n * dstCols;
    int sr = -1;
    if (k < seg1) sr = k;
    else if (k >= seg2start && (k - seg2start) < (srcRows - seg1)) sr = seg1 + (k - seg2start);
    u16 v = 0;
    if (n < srcCols && sr >= 0) v = f2bf(src[(long long)sr * srcCols + n]);
    dst[idx] = v;
}

__global__ __launch_bounds__(256)
void zero_pool(float* __restrict__ p)
{
    p[blockIdx.x * 256 + threadIdx.x] = 0.f;
}

// mask[b][l] = (l < count_nonzero(x[b,:])) ? 1 : 0
__global__ __launch_bounds__(256)
void make_mask(const int* __restrict__ x, float* __restrict__ mask)
{
    const int b = blockIdx.x;
    const int t = threadIdx.x;
    int nz = (x[b * LSEQ + t] != 0) ? 1 : 0;
#pragma unroll
    for (int o = 32; o; o >>= 1) nz += __shfl_xor(nz, o, 64);
    __shared__ int red[4];
    if ((t & 63) == 0) red[t >> 6] = nz;
    __syncthreads();
    const int size = red[0] + red[1] + red[2] + red[3];
    mask[b * LSEQ + t] = (t < size) ? 1.0f : 0.0f;
}

// gather + L2-normalize -> H[row][0:320] bf16 (cols 300-319 zero), pitch 640
__global__ __launch_bounds__(256)
void gather_norm(const int* __restrict__ x, const float* __restrict__ emb,
                 u16* __restrict__ h)
{
    const int t = threadIdx.x;
    const int lane = t & 63;
    const long long row = (long long)blockIdx.x * 4 + (t >> 6);
    const int tok = x[row];
    const float* er = emb + (long long)tok * 300;
    float vals[5];
    float ss = 0.f;
#pragma unroll
    for (int i = 0; i < 5; ++i) {
        const int c = lane + i * 64;
        const float v = (c < 300) ? er[c] : 0.f;
        vals[i] = v;
        ss = fmaf(v, v, ss);
    }
#pragma unroll
    for (int o = 32; o; o >>= 1) ss += __shfl_xor(ss, o, 64);
    const float inv = 1.0f / sqrtf(ss);
    u16* out = h + row * 640;
#pragma unroll
    for (int i = 0; i < 5; ++i) {
        const int c = lane + i * 64;
        out[c] = f2bf(vals[i] * inv);
    }
}

// in-place row softmax over 256 (bf16), optional distance bias
template<bool DBIAS>
__global__ __launch_bounds__(256)
void row_softmax(u16* __restrict__ buf, const float* __restrict__ b_dist)
{
    const long long row = blockIdx.x;
    const int i = (int)(row & 255);
    const int t = threadIdx.x;
    float v = bf2f(buf[row * 256 + t]);
    if (DBIAS) {
        const int d = (i > t) ? (i - t) : (t - i);
        if (d >= 10) v += b_dist[0];
    }
    float m = v;
#pragma unroll
    for (int o = 32; o; o >>= 1) m = fmaxf(m, __shfl_xor(m, o, 64));
    __shared__ float redm[4];
    if ((t & 63) == 0) redm[t >> 6] = m;
    __syncthreads();
    m = fmaxf(fmaxf(redm[0], redm[1]), fmaxf(redm[2], redm[3]));
    const float e = expf(v - m);
    float s = e;
#pragma unroll
    for (int o = 32; o; o >>= 1) s += __shfl_xor(s, o, 64);
    __shared__ float reds[4];
    if ((t & 63) == 0) reds[t >> 6] = s;
    __syncthreads();
    s = reds[0] + reds[1] + reds[2] + reds[3];
    buf[row * 256 + t] = f2bf(e / s);
}

__global__ __launch_bounds__(256)
void final_fc(const float* __restrict__ pooled, const float* __restrict__ Wg,
              const float* __restrict__ bg, float* __restrict__ out)
{
    const int b = blockIdx.x;
    const int t = threadIdx.x;
    float a0 = 0.f, a1 = 0.f, a2 = 0.f;
    for (int k = t; k < 800; k += 256) {
        const float p = pooled[(long long)b * 800 + k];
        a0 = fmaf(p, Wg[k * 3 + 0], a0);
        a1 = fmaf(p, Wg[k * 3 + 1], a1);
        a2 = fmaf(p, Wg[k * 3 + 2], a2);
    }
#pragma unroll
    for (int o = 32; o; o >>= 1) {
        a0 += __shfl_xor(a0, o, 64);
        a1 += __shfl_xor(a1, o, 64);
        a2 += __shfl_xor(a2, o, 64);
    }
    __shared__ float r0[4], r1[4], r2[4];
    if ((t & 63) == 0) { r0[t >> 6] = a0; r1[t >> 6] = a1; r2[t >> 6] = a2; }
    __syncthreads();
    if (t == 0) {
        out[b * 3 + 0] = r0[0] + r0[1] + r0[2] + r0[3] + bg[0];
        out[b * 3 + 1] = r1[0] + r1[1] + r1[2] + r1[3] + bg[1];
        out[b * 3 + 2] = r2[0] + r2[1] + r2[2] + r2[3] + bg[2];
    }
}

// ---------------------------------------------------------------------------
extern "C" void kernel_launch(void* const* d_in, const int* in_sizes, int n_in,
                              void* d_out, int out_size, void* d_ws, size_t ws_size,
                              hipStream_t stream)
{
    (void)in_sizes; (void)n_in; (void)out_size; (void)ws_size;

    const int*   x1     = (const int*)  d_in[0];
    const int*   x2     = (const int*)  d_in[1];
    const float* emb    = (const float*)d_in[2];
    const float* Wi     = (const float*)d_in[3];
    const float* bi     = (const float*)d_in[4];
    const float* b_dist = (const float*)d_in[5];
    const float* Wp     = (const float*)d_in[6];
    const float* bp     = (const float*)d_in[7];
    const float* Wa     = (const float*)d_in[8];
    const float* ba     = (const float*)d_in[9];
    const float* Wc     = (const float*)d_in[10];
    const float* bc     = (const float*)d_in[11];
    const float* Wg     = (const float*)d_in[12];
    const float* bg     = (const float*)d_in[13];
    float* out = (float*)d_out;

    // ---- workspace (bf16 unless noted), all bases 16B-aligned -----------
    u16* wsu  = (u16*)d_ws;
    u16* H    = wsu;               // [32768][640]: e(0:300)|0|xp(320:620)|0
    u16* CMP1 = wsu + 20971520;    // [32768][448]: P1(0:200)|beta(200:400)|0
    u16* CMP2 = wsu + 35651584;    // [32768][448]: P2 | alpha | 0
    u16* F    = wsu + 50331648;    // [32768][256]: f / a1
    u16* ATT  = wsu + 58720256;    // [32768][256]: a2
    u16* SIM  = wsu + 67108864;    // [128][256][256]
    u16* SS   = wsu + 75497472;    // [128][256][256]
    u16* WiT  = wsu + 83886080;    // [256][320]
    u16* WaT  = wsu + 83968000;    // [256][256]
    u16* WpT  = wsu + 84033536;    // [256][640]
    u16* WcT  = wsu + 84197376;    // [512][448]
    float* fb = (float*)(wsu + 84426752);
    float* POOL = fb;              // [128][800]
    float* M1f  = fb + 102400;     // [128][256]
    float* M2f  = fb + 135168;

    const long long sL = 65536;    // 256*256 per-batch stride (F/ATT/SIM/SS)
    const long long sC448 = 114688;   // 256*448
    const long long sH = 163840;      // 256*640

    zero_pool<<<400, 256, 0, stream>>>(POOL);
    make_mask<<<NB, 256, 0, stream>>>(x1, M1f);
    make_mask<<<NB, 256, 0, stream>>>(x2, M2f);
    prep_w<<<(256 * 320) / 256, 256, 0, stream>>>(Wi, 300, 200, WiT, 320, 256 * 320, 300, 320);
    prep_w<<<(256 * 256) / 256, 256, 0, stream>>>(Wa, 200, 200, WaT, 256, 256 * 256, 200, 256);
    prep_w<<<(256 * 640) / 256, 256, 0, stream>>>(Wp, 600, 200, WpT, 640, 256 * 640, 300, 320);
    prep_w<<<(512 * 448) / 256, 256, 0, stream>>>(Wc, 400, 400, WcT, 448, 512 * 448, 400, 448);

    // ---- stage A per side ------------------------------------------------
    for (int s = 0; s < 2; ++s) {
        const int* xs = s ? x2 : x1;
        u16* CMP = s ? CMP2 : CMP1;
        gather_norm<<<8192, 256, 0, stream>>>(xs, emb, H);
        // f = relu(e @ Wi + bi) -> F
        gemm<0, true, true, false, false, false><<<dim3(1, 256, 1), 512, 0, stream>>>(
            H, 640, 0, WiT, 320, 0, F, 256, 0, bi, 200,
            nullptr, nullptr, nullptr, 0, nullptr, 320, 0, 256);
        // att = f @ f^T (batched) -> SIM
        gemm<0, false, false, false, false, true><<<dim3(1, 2, NB), 512, 0, stream>>>(
            F, 256, sL, F, 256, sL, SIM, 256, sL, nullptr, 0,
            nullptr, nullptr, nullptr, 0, nullptr, 256, 0, 256);
        row_softmax<true><<<32768, 256, 0, stream>>>(SIM, b_dist);
        // xp = softmax(att) @ e -> H cols 320:640
        gemm<1, false, false, false, false, true><<<dim3(2, 2, NB), 512, 0, stream>>>(
            SIM, 256, sL, H, 640, sH, H + 320, 640, sH, nullptr, 0,
            nullptr, nullptr, nullptr, 0, nullptr, 256, 320, 320);
        // P = h @ Wp + bp -> CMP cols 0:256
        gemm<0, true, false, false, false, false><<<dim3(1, 256, 1), 512, 0, stream>>>(
            H, 640, 0, WpT, 640, 0, CMP, 448, 0, bp, 200,
            nullptr, nullptr, nullptr, 0, nullptr, 640, 0, 256);
    }

    // ---- cross attention ---------------------------------------------------
    // a1 = relu(P1 @ Wa + ba) -> F ; a2 -> ATT
    gemm<0, true, true, false, false, false><<<dim3(1, 256, 1), 512, 0, stream>>>(
        CMP1, 448, 0, WaT, 256, 0, F, 256, 0, ba, 200,
        nullptr, nullptr, nullptr, 0, nullptr, 256, 0, 256);
    gemm<0, true, true, false, false, false><<<dim3(1, 256, 1), 512, 0, stream>>>(
        CMP2, 448, 0, WaT, 256, 0, ATT, 256, 0, ba, 200,
        nullptr, nullptr, nullptr, 0, nullptr, 256, 0, 256);
    // sim = (a1 @ a2^T) * m1 x m2 -> SIM ; sim^T = (a2 @ a1^T) * m2 x m1 -> SS
    gemm<0, false, false, true, false, true><<<dim3(1, 2, NB), 512, 0, stream>>>(
        F, 256, sL, ATT, 256, sL, SIM, 256, sL, nullptr, 0,
        M1f, M2f, nullptr, 0, nullptr, 256, 0, 256);
    gemm<0, false, false, true, false, true><<<dim3(1, 2, NB), 512, 0, stream>>>(
        ATT, 256, sL, F, 256, sL, SS, 256, sL, nullptr, 0,
        M2f, M1f, nullptr, 0, nullptr, 256, 0, 256);
    row_softmax<false><<<32768, 256, 0, stream>>>(SIM, nullptr);
    row_softmax<false><<<32768, 256, 0, stream>>>(SS, nullptr);
    // beta = softmax(sim) @ P2 -> CMP1 cols 200:448 (cols>=400 become 0)
    gemm<1, false, false, false, false, true><<<dim3(1, 2, NB), 512, 0, stream>>>(
        SIM, 256, sL, CMP2, 448, sC448, CMP1 + 200, 448, sC448, nullptr, 0,
        nullptr, nullptr, nullptr, 0, nullptr, 256, 200, 248);
    // alpha = softmax(sim^T) @ P1 -> CMP2 cols 200:448
    gemm<1, false, false, false, false, true><<<dim3(1, 2, NB), 512, 0, stream>>>(
        SS, 256, sL, CMP1, 448, sC448, CMP2 + 200, 448, sC448, nullptr, 0,
        nullptr, nullptr, nullptr, 0, nullptr, 256, 200, 248);

    // ---- fused compare + masked pool ---------------------------------------
    gemm<0, true, true, false, true, false><<<dim3(2, 256, 1), 512, 0, stream>>>(
        CMP1, 448, 0, WcT, 448, 0, nullptr, 0, 0, bc, 400,
        nullptr, nullptr, POOL, 0, M1f, 448, 0, 400);
    gemm<0, true, true, false, true, false><<<dim3(2, 256, 1), 512, 0, stream>>>(
        CMP2, 448, 0, WcT, 448, 0, nullptr, 0, 0, bc, 400,
        nullptr, nullptr, POOL, 400, M2f, 448, 0, 400);

    final_fc<<<NB, 256, 0, stream>>>(POOL, Wg, bg, out);
}